// Round 23
// baseline (98.954 us; speedup 1.0000x reference)
//
#include <hip/hip_runtime.h>
#include <float.h>

// VectorQuantizer on MI355X — MFMA f16 screen + compacted np-f32 rescue.
// R23: SINGLE-WAVE blocks (64 threads), 16 pixels/block, 4096 blocks.
//
// Gang-size trend: 8-wave 43.3/43.7 -> 4-wave 41.5 (R22). Endpoint: 1-wave
// blocks — zero barrier convoys (lone wave self-syncs), no cross-wave merge,
// 4096 independent blocks to backfill latency phases. Per-wave screen covers
// all 512 codes (32 MFMA-tile iters, hv[64] f16x2 ~ 64 VGPRs); the VGPR-64
// tier cliff (R19/R20) doesn't apply: 64-thread blocks need only 4 waves/SIMD,
// so __launch_bounds__(64,4) grants a 128-VGPR budget (no squeeze, no spill).
// thr = own min over all 512 + W == previous merged min -> identical candidate
// set -> bit-identical idx (numerics validated R13-R22, absmax 7.63e-6).
#pragma clang fp contract(off)

#define K_EMB   512
#define D_EMB   64
#define Q_ELEMS 4194304   // 64 * 64 * 32 * 32
#define PPB     16        // pixels per block
#define NBLK    4096      // 65536 / 16
#define W_SCR   0.5f      // rescue window, scaled (512x) — validated R13-R22
#define XROW    65        // xf row stride (odd -> bank-spread)
#define LCAP    256       // candidate list capacity (avg ~19/block)

typedef _Float16 f16x8 __attribute__((ext_vector_type(8)));
typedef _Float16 f16x2 __attribute__((ext_vector_type(2)));
typedef float    f32x4 __attribute__((ext_vector_type(4)));

// numpy pairwise_sum order for n=64 contiguous f32, summing PRE-ROUNDED squares.
__device__ __forceinline__ float np_sumsq64(const float* v) {
    float r[8];
    #pragma unroll
    for (int j = 0; j < 8; ++j) r[j] = v[j] * v[j];
    #pragma unroll
    for (int i = 8; i < 64; i += 8) {
        #pragma unroll
        for (int j = 0; j < 8; ++j) {
            float s = v[i + j] * v[i + j];
            r[j] = r[j] + s;
        }
    }
    return ((r[0] + r[1]) + (r[2] + r[3])) + ((r[4] + r[5]) + (r[6] + r[7]));
}

// ---------------- kernel 1: t2 (np-exact), 512-scaled t2, A-fragment table ----
// embA slot g=(t*2+s)*64+l: lane l's A-frag for code tile t, k-step s:
// code=t*16+(l&15), dims d = s*32+(l>>4)*8 .. +8, values u=512e (pow2-exact).
__global__ __launch_bounds__(256) void vq_prep(const float* __restrict__ emb,
                                               float* __restrict__ t2,
                                               float* __restrict__ t2s512,
                                               f16x8* __restrict__ embA) {
    const int g = blockIdx.x * 256 + threadIdx.x;
    if (g < K_EMB) {
        const float* ep = emb + (g << 6);
        float s = np_sumsq64(ep);
        t2[g]     = s;
        t2s512[g] = 512.0f * s;
    }
    if (g < 4096) {
        const int t = g >> 7;
        const int s = (g >> 6) & 1;
        const int l = g & 63;
        const int code  = t * 16 + (l & 15);
        const int dbase = s * 32 + ((l >> 4) << 3);
        const float* ep = emb + (code << 6) + dbase;
        f16x8 a;
        #pragma unroll
        for (int i = 0; i < 8; ++i) a[i] = (_Float16)(512.0f * ep[i]);
        embA[g] = a;
    }
}

// ---------------- kernel 2: main VQ (1 wave, 16 pixels, all 512 codes) -------
__global__ __launch_bounds__(64, 4) void vq_main(const float* __restrict__ x,
                                                 const float* __restrict__ emb,
                                                 const float* __restrict__ t2,
                                                 const float* __restrict__ t2s512,
                                                 const f16x8* __restrict__ embA,
                                                 float* __restrict__ out_q,
                                                 float* __restrict__ out_idx,
                                                 float* __restrict__ partial) {
    const int lane = threadIdx.x;               // 0..63
    const int p16  = lane & 15;                 // pixel in tile
    const int bg   = lane >> 4;                 // code-slice / dim-quarter group

    __shared__ float xf[PPB * XROW];            // f32 x-tile (4.2 KB)
    __shared__ float t1s[PPB];
    __shared__ unsigned long long keys[PPB];
    __shared__ int   list[LCAP];
    __shared__ int   lcnt;

    // ---- stage: lane (p16, bg) loads dims bg*16 .. bg*16+15 of pixel p16 ----
    const int np_ = blockIdx.x * PPB + p16;
    const float* __restrict__ xs = x + (np_ >> 10) * 65536 + (np_ & 1023);
    #pragma unroll
    for (int j = 0; j < 16; ++j) {
        const int d = bg * 16 + j;
        xf[p16 * XROW + d] = xs[d * 1024];
    }
    if (lane < PPB) keys[lane] = 0xFFFFFFFFFFFFFFFFull;
    if (lane == 0) lcnt = 0;
    __syncthreads();                            // single wave: cheap waitcnt+retire

    // ---- t1 per pixel (np-exact, contiguous LDS row) ----
    if (lane < PPB) t1s[lane] = np_sumsq64(&xf[lane * XROW]);

    // ---- B-fragments for the 16 pixels (RN f16 cvt from LDS f32) ----
    f16x8 b0, b1;
    #pragma unroll
    for (int i = 0; i < 8; ++i) {
        b0[i] = (_Float16)xf[p16 * XROW + 0 * 32 + bg * 8 + i];
        b1[i] = (_Float16)xf[p16 * XROW + 1 * 32 + bg * 8 + i];
    }

    const f32x4 czero = {0.f, 0.f, 0.f, 0.f};
    const float4* __restrict__ t2s4 = (const float4*)t2s512;

    // ---- pass 1: screen ALL 512 codes; pack dists to f16 regs; track min ----
    f16x2 hv[64];                               // 128 screen values, packed
    float m = FLT_MAX;
    #pragma unroll
    for (int t = 0; t < 32; ++t) {
        f16x8 a0 = embA[(t * 2 + 0) * 64 + lane];
        f16x8 a1 = embA[(t * 2 + 1) * 64 + lane];
        f32x4 c = __builtin_amdgcn_mfma_f32_16x16x32_f16(a0, b0, czero, 0, 0, 0);
        c = __builtin_amdgcn_mfma_f32_16x16x32_f16(a1, b1, c, 0, 0, 0);
        float4 tv = t2s4[t * 4 + bg];
        float s0 = fmaf(-2.f, c[0], tv.x);
        float s1 = fmaf(-2.f, c[1], tv.y);
        float s2 = fmaf(-2.f, c[2], tv.z);
        float s3 = fmaf(-2.f, c[3], tv.w);
        f16x2 p01, p23;
        p01[0] = (_Float16)s0; p01[1] = (_Float16)s1;
        p23[0] = (_Float16)s2; p23[1] = (_Float16)s3;
        hv[t * 2 + 0] = p01;
        hv[t * 2 + 1] = p23;
        m = fminf(m, fminf(fminf(s0, s1), fminf(s2, s3)));
    }
    // per-pixel min over the 4 lane-groups holding this pixel
    m = fminf(m, __shfl_xor(m, 16));
    m = fminf(m, __shfl_xor(m, 32));
    const float thr = m + W_SCR;

    // ---- pass 2: pure register scan, COLLECT candidates ----
    #pragma unroll
    for (int t = 0; t < 32; ++t) {
        f16x2 p01 = hv[t * 2 + 0];
        f16x2 p23 = hv[t * 2 + 1];
        float s0 = (float)p01[0];
        float s1 = (float)p01[1];
        float s2 = (float)p23[0];
        float s3 = (float)p23[1];
        const int kb = t * 16 + bg * 4;
        if (s0 < thr) { int s = atomicAdd(&lcnt, 1); if (s < LCAP) list[s] = p16 * 512 + kb + 0; }
        if (s1 < thr) { int s = atomicAdd(&lcnt, 1); if (s < LCAP) list[s] = p16 * 512 + kb + 1; }
        if (s2 < thr) { int s = atomicAdd(&lcnt, 1); if (s < LCAP) list[s] = p16 * 512 + kb + 2; }
        if (s3 < thr) { int s = atomicAdd(&lcnt, 1); if (s < LCAP) list[s] = p16 * 512 + kb + 3; }
    }
    __syncthreads();

    // ---- rescue: one candidate per lane, operands from LDS ----
    const int ncand = min(lcnt, LCAP);
    for (int i = lane; i < ncand; i += 64) {
        const int v = list[i];
        const int p = v >> 9;
        const int k = v & 511;
        const float* xp = &xf[p * XROW];
        const float* __restrict__ ep = emb + (k << 6);
        float a = 0.f;
        #pragma unroll
        for (int d = 0; d < D_EMB; ++d) a = fmaf(xp[d], ep[d], a);
        float X = t1s[p] + t2[k];
        float dnp = fmaf(-2.f, a, X);           // exact np-f32 dist
        unsigned long long key =
            ((unsigned long long)__float_as_uint(dnp) << 32) | (unsigned)k;
        atomicMin(&keys[p], key);
    }
    __syncthreads();

    // ---- epilogue: lane (p16, bg): dims bg*16..+15; loss partial ----
    float acc = 0.f;
    {
        const int kw = (int)(unsigned)(keys[p16] & 0xFFFFFFFFull);
        float* __restrict__ qp = out_q + (np_ >> 10) * 65536 + (np_ & 1023);
        const float4* __restrict__ eq = (const float4*)(emb + (kw << 6) + bg * 16);
        #pragma unroll
        for (int j4 = 0; j4 < 4; ++j4) {
            float4 qv = eq[j4];
            const int d = bg * 16 + j4 * 4;
            float f0 = qv.x - xf[p16 * XROW + d + 0];
            float f1 = qv.y - xf[p16 * XROW + d + 1];
            float f2 = qv.z - xf[p16 * XROW + d + 2];
            float f3 = qv.w - xf[p16 * XROW + d + 3];
            acc = fmaf(f0, f0, acc);
            acc = fmaf(f1, f1, acc);
            acc = fmaf(f2, f2, acc);
            acc = fmaf(f3, f3, acc);
            qp[(d + 0) * 1024] = qv.x;
            qp[(d + 1) * 1024] = qv.y;
            qp[(d + 2) * 1024] = qv.z;
            qp[(d + 3) * 1024] = qv.w;
        }
        if (bg == 0) out_idx[np_] = (float)kw;
    }

    // wave loss reduce (single wave -> no LDS)
    #pragma unroll
    for (int off = 32; off > 0; off >>= 1) acc += __shfl_down(acc, off);
    if (lane == 0) partial[blockIdx.x] = acc;
}

// ---------------- kernel 3: finalize loss over 4096 partials ----------------
__global__ __launch_bounds__(256) void vq_loss(const float* __restrict__ partial,
                                               float* __restrict__ loss) {
    const int t = threadIdx.x;
    float v = 0.f;
    #pragma unroll
    for (int i = 0; i < 16; i += 2) {
        float a = partial[t + (i + 0) * 256];
        float b = partial[t + (i + 1) * 256];
        v = v + (a + b);
    }
    #pragma unroll
    for (int off = 32; off > 0; off >>= 1) v += __shfl_down(v, off);
    __shared__ float red[4];
    if ((t & 63) == 0) red[t >> 6] = v;
    __syncthreads();
    if (t == 0)
        loss[0] = 1.25f * ((red[0] + red[1]) + (red[2] + red[3])) / (float)Q_ELEMS;
}

extern "C" void kernel_launch(void* const* d_in, const int* in_sizes, int n_in,
                              void* d_out, int out_size, void* d_ws, size_t ws_size,
                              hipStream_t stream) {
    const float* x   = (const float*)d_in[0];   // [64,64,32,32] NCHW
    const float* emb = (const float*)d_in[1];   // [512,64]

    float* out_q    = (float*)d_out;                // [4194304]
    float* out_loss = (float*)d_out + Q_ELEMS;      // [1]
    float* out_idx  = (float*)d_out + Q_ELEMS + 1;  // [65536] as float

    float* t2      = (float*)d_ws;                  // 512
    float* t2s512  = t2 + K_EMB;                    // 512
    float* partial = t2s512 + K_EMB;                // 4096
    f16x8* embA    = (f16x8*)(partial + 4096);      // 20480B offset, 16B-aligned

    vq_prep<<<16, 256, 0, stream>>>(emb, t2, t2s512, embA);
    vq_main<<<NBLK, 64, 0, stream>>>(x, emb, t2, t2s512, embA,
                                     out_q, out_idx, partial);
    vq_loss<<<1, 256, 0, stream>>>(partial, out_loss);
}

// Round 24
// 41.325 us; speedup vs baseline: 2.3945x; 2.3945x over previous
//
#include <hip/hip_runtime.h>
#include <float.h>

// VectorQuantizer on MI355X — MFMA f16 screen (register-held) + compacted np-f32
// rescue, x in LDS. EXACT RESTORE OF R22 (session best: 41.5us).
// 256-thread blocks (4 waves), 32 pixels/block, 2048 blocks.
//
// Gang-size sweep complete: 8-wave 43.3/43.7 (R18/R21), 4-wave 41.5 (R22),
// 1-wave 98.9 (R23: hv[64] spilled to scratch at the allocator's 64-VGPR
// target — 343MB spill traffic — and per-block embA restreaming 256MB).
// R22 is the minimum. Remaining time is dispatch/latency-structural:
// all pipes <20% busy, occupancy ~37% regardless of shape, memory floor ~5us.
#pragma clang fp contract(off)

#define K_EMB   512
#define D_EMB   64
#define Q_ELEMS 4194304   // 64 * 64 * 32 * 32
#define PPB     32        // pixels per block
#define NBLK    2048      // 65536 / 32
#define W_SCR   0.5f      // rescue window, scaled (512x) — validated R13-R23
#define XROW    65        // xf row stride (odd -> bank-spread)
#define LCAP    512       // candidate list capacity (avg ~39/block)

typedef _Float16 f16x8 __attribute__((ext_vector_type(8)));
typedef _Float16 f16x2 __attribute__((ext_vector_type(2)));
typedef float    f32x4 __attribute__((ext_vector_type(4)));

// numpy pairwise_sum order for n=64 contiguous f32, summing PRE-ROUNDED squares.
__device__ __forceinline__ float np_sumsq64(const float* v) {
    float r[8];
    #pragma unroll
    for (int j = 0; j < 8; ++j) r[j] = v[j] * v[j];
    #pragma unroll
    for (int i = 8; i < 64; i += 8) {
        #pragma unroll
        for (int j = 0; j < 8; ++j) {
            float s = v[i + j] * v[i + j];
            r[j] = r[j] + s;
        }
    }
    return ((r[0] + r[1]) + (r[2] + r[3])) + ((r[4] + r[5]) + (r[6] + r[7]));
}

// ---------------- kernel 1: t2 (np-exact), 512-scaled t2, A-fragment table ----
// embA slot g=(t*2+s)*64+l: lane l's A-frag for code tile t, k-step s:
// code=t*16+(l&15), dims d = s*32+(l>>4)*8 .. +8, values u=512e (pow2-exact).
__global__ __launch_bounds__(256) void vq_prep(const float* __restrict__ emb,
                                               float* __restrict__ t2,
                                               float* __restrict__ t2s512,
                                               f16x8* __restrict__ embA) {
    const int g = blockIdx.x * 256 + threadIdx.x;
    if (g < K_EMB) {
        const float* ep = emb + (g << 6);
        float s = np_sumsq64(ep);
        t2[g]     = s;
        t2s512[g] = 512.0f * s;
    }
    if (g < 4096) {
        const int t = g >> 7;
        const int s = (g >> 6) & 1;
        const int l = g & 63;
        const int code  = t * 16 + (l & 15);
        const int dbase = s * 32 + ((l >> 4) << 3);
        const float* ep = emb + (code << 6) + dbase;
        f16x8 a;
        #pragma unroll
        for (int i = 0; i < 8; ++i) a[i] = (_Float16)(512.0f * ep[i]);
        embA[g] = a;
    }
}

// ---------------- kernel 2: main VQ (4 waves: pixel-tile x code-half) ---------
__global__ __launch_bounds__(256) void vq_main(const float* __restrict__ x,
                                               const float* __restrict__ emb,
                                               const float* __restrict__ t2,
                                               const float* __restrict__ t2s512,
                                               const f16x8* __restrict__ embA,
                                               float* __restrict__ out_q,
                                               float* __restrict__ out_idx,
                                               float* __restrict__ partial) {
    const int tid  = threadIdx.x;
    const int lane = tid & 63;
    const int wave = tid >> 6;                  // 0..3
    const int pt   = wave & 1;                  // pixel-tile (16 pixels)
    const int ch   = wave >> 1;                 // code-half (16 MFMA tiles)

    __shared__ float xf[PPB * XROW];            // f32 x-tile, staged ONCE (8.3 KB)
    __shared__ float t1s[PPB];                  // np-exact t1 per pixel
    __shared__ float mwv[4][16];                // per-(wave, pixel-in-tile) min
    __shared__ unsigned long long keys[PPB];    // (bits(dist)<<32)|k per pixel
    __shared__ int   list[LCAP];                // packed candidates p*512+k
    __shared__ int   lcnt;
    __shared__ float red[4];

    // ---- stage: thread (p = tid&31, oct = tid>>5) loads 8 dims, coalesced ----
    {
        const int p   = tid & 31;
        const int oct = tid >> 5;               // 0..7
        const int np_ = blockIdx.x * PPB + p;
        const float* __restrict__ xs = x + (np_ >> 10) * 65536 + (np_ & 1023);
        #pragma unroll
        for (int j = 0; j < 8; ++j) {
            const int d = oct * 8 + j;
            xf[p * XROW + d] = xs[d * 1024];
        }
        if (tid < PPB) keys[tid] = 0xFFFFFFFFFFFFFFFFull;
        if (tid == 0) lcnt = 0;
    }
    __syncthreads();

    // ---- t1 per pixel (np-exact, contiguous LDS row) ----
    if (tid < PPB) t1s[tid] = np_sumsq64(&xf[tid * XROW]);
    // (consumed by rescue, after the post-pass2 barrier)

    // ---- B-fragments for this wave's 16 pixels (RN f16 cvt from LDS f32) ----
    const int bp = 16 * pt + (lane & 15);       // pixel row (0..31)
    const int bg = lane >> 4;                   // code-slice group
    f16x8 b0, b1;
    #pragma unroll
    for (int i = 0; i < 8; ++i) {
        b0[i] = (_Float16)xf[bp * XROW + 0 * 32 + bg * 8 + i];
        b1[i] = (_Float16)xf[bp * XROW + 1 * 32 + bg * 8 + i];
    }

    const f32x4 czero = {0.f, 0.f, 0.f, 0.f};
    const float4* __restrict__ t2s4 = (const float4*)t2s512;
    const int t0 = ch * 16;                     // this wave's 16 code tiles

    // ---- pass 1: screen 256 codes; pack dists to f16 regs; track min ----
    f16x2 hv[32];                               // 64 screen values, packed
    float m = FLT_MAX;
    #pragma unroll
    for (int tt = 0; tt < 16; ++tt) {
        const int t = t0 + tt;
        f16x8 a0 = embA[(t * 2 + 0) * 64 + lane];
        f16x8 a1 = embA[(t * 2 + 1) * 64 + lane];
        f32x4 c = __builtin_amdgcn_mfma_f32_16x16x32_f16(a0, b0, czero, 0, 0, 0);
        c = __builtin_amdgcn_mfma_f32_16x16x32_f16(a1, b1, c, 0, 0, 0);
        float4 tv = t2s4[t * 4 + bg];
        float s0 = fmaf(-2.f, c[0], tv.x);
        float s1 = fmaf(-2.f, c[1], tv.y);
        float s2 = fmaf(-2.f, c[2], tv.z);
        float s3 = fmaf(-2.f, c[3], tv.w);
        f16x2 p01, p23;
        p01[0] = (_Float16)s0; p01[1] = (_Float16)s1;
        p23[0] = (_Float16)s2; p23[1] = (_Float16)s3;
        hv[tt * 2 + 0] = p01;
        hv[tt * 2 + 1] = p23;
        m = fminf(m, fminf(fminf(s0, s1), fminf(s2, s3)));
    }
    m = fminf(m, __shfl_xor(m, 16));
    m = fminf(m, __shfl_xor(m, 32));
    if (lane < 16) mwv[wave][lane] = m;         // per-wave per-pixel half-min
    __syncthreads();

    // per-pixel global threshold: min over the two waves owning this pixel-tile
    const float thr = fminf(mwv[pt][lane & 15], mwv[pt + 2][lane & 15]) + W_SCR;

    // ---- pass 2: pure register scan, COLLECT candidates ----
    #pragma unroll
    for (int tt = 0; tt < 16; ++tt) {
        f16x2 p01 = hv[tt * 2 + 0];
        f16x2 p23 = hv[tt * 2 + 1];
        float s0 = (float)p01[0];
        float s1 = (float)p01[1];
        float s2 = (float)p23[0];
        float s3 = (float)p23[1];
        const int kb = (t0 + tt) * 16 + bg * 4;
        if (s0 < thr) { int s = atomicAdd(&lcnt, 1); if (s < LCAP) list[s] = bp * 512 + kb + 0; }
        if (s1 < thr) { int s = atomicAdd(&lcnt, 1); if (s < LCAP) list[s] = bp * 512 + kb + 1; }
        if (s2 < thr) { int s = atomicAdd(&lcnt, 1); if (s < LCAP) list[s] = bp * 512 + kb + 2; }
        if (s3 < thr) { int s = atomicAdd(&lcnt, 1); if (s < LCAP) list[s] = bp * 512 + kb + 3; }
    }
    __syncthreads();

    // ---- rescue: one candidate per lane, operands from LDS ----
    const int ncand = min(lcnt, LCAP);
    for (int i = tid; i < ncand; i += 256) {
        const int v = list[i];
        const int p = v >> 9;
        const int k = v & 511;
        const float* xp = &xf[p * XROW];
        const float* __restrict__ ep = emb + (k << 6);
        float a = 0.f;
        #pragma unroll
        for (int d = 0; d < D_EMB; ++d) a = fmaf(xp[d], ep[d], a);
        float X = t1s[p] + t2[k];
        float dnp = fmaf(-2.f, a, X);           // exact np-f32 dist
        unsigned long long key =
            ((unsigned long long)__float_as_uint(dnp) << 32) | (unsigned)k;
        atomicMin(&keys[p], key);
    }
    __syncthreads();

    // ---- epilogue: thread (p = tid&31, q = tid>>5): 8 dims; loss partial ----
    float acc = 0.f;
    {
        const int p = tid & 31;
        const int q = tid >> 5;
        const int n2 = blockIdx.x * PPB + p;
        const int kw = (int)(unsigned)(keys[p] & 0xFFFFFFFFull);
        float* __restrict__ qp = out_q + (n2 >> 10) * 65536 + (n2 & 1023);
        const float4* __restrict__ eq = (const float4*)(emb + (kw << 6) + q * 8);
        #pragma unroll
        for (int j4 = 0; j4 < 2; ++j4) {
            float4 qv = eq[j4];
            const int d = q * 8 + j4 * 4;
            float f0 = qv.x - xf[p * XROW + d + 0];
            float f1 = qv.y - xf[p * XROW + d + 1];
            float f2 = qv.z - xf[p * XROW + d + 2];
            float f3 = qv.w - xf[p * XROW + d + 3];
            acc = fmaf(f0, f0, acc);
            acc = fmaf(f1, f1, acc);
            acc = fmaf(f2, f2, acc);
            acc = fmaf(f3, f3, acc);
            qp[(d + 0) * 1024] = qv.x;
            qp[(d + 1) * 1024] = qv.y;
            qp[(d + 2) * 1024] = qv.z;
            qp[(d + 3) * 1024] = qv.w;
        }
        if (q == 0) out_idx[n2] = (float)kw;
    }

    // block loss partial: per-wave shuffle reduce, then LDS across 4 waves
    #pragma unroll
    for (int off = 32; off > 0; off >>= 1) acc += __shfl_down(acc, off);
    if (lane == 0) red[wave] = acc;
    __syncthreads();
    if (tid == 0)
        partial[blockIdx.x] = (red[0] + red[1]) + (red[2] + red[3]);
}

// ---------------- kernel 3: finalize loss over 2048 partials ----------------
__global__ __launch_bounds__(256) void vq_loss(const float* __restrict__ partial,
                                               float* __restrict__ loss) {
    const int t = threadIdx.x;
    float v = ((partial[t] + partial[t + 256]) + (partial[t + 512] + partial[t + 768]))
            + ((partial[t + 1024] + partial[t + 1280])
               + (partial[t + 1536] + partial[t + 1792]));
    #pragma unroll
    for (int off = 32; off > 0; off >>= 1) v += __shfl_down(v, off);
    __shared__ float red[4];
    if ((t & 63) == 0) red[t >> 6] = v;
    __syncthreads();
    if (t == 0)
        loss[0] = 1.25f * ((red[0] + red[1]) + (red[2] + red[3])) / (float)Q_ELEMS;
}

extern "C" void kernel_launch(void* const* d_in, const int* in_sizes, int n_in,
                              void* d_out, int out_size, void* d_ws, size_t ws_size,
                              hipStream_t stream) {
    const float* x   = (const float*)d_in[0];   // [64,64,32,32] NCHW
    const float* emb = (const float*)d_in[1];   // [512,64]

    float* out_q    = (float*)d_out;                // [4194304]
    float* out_loss = (float*)d_out + Q_ELEMS;      // [1]
    float* out_idx  = (float*)d_out + Q_ELEMS + 1;  // [65536] as float

    float* t2      = (float*)d_ws;                  // 512
    float* t2s512  = t2 + K_EMB;                    // 512
    float* partial = t2s512 + K_EMB;                // 2048
    f16x8* embA    = (f16x8*)(partial + 2048);      // 12288B offset, 16B-aligned

    vq_prep<<<16, 256, 0, stream>>>(emb, t2, t2s512, embA);
    vq_main<<<NBLK, 256, 0, stream>>>(x, emb, t2, t2s512, embA,
                                      out_q, out_idx, partial);
    vq_loss<<<1, 256, 0, stream>>>(partial, out_loss);
}